// Round 3
// baseline (493.662 us; speedup 1.0000x reference)
//
#include <hip/hip_runtime.h>

// HyperConnections fused kernel (fp32), wave-per-token, params staged in LDS.
//
// out[t,:] = residual[t,:] * (SB + E*tanh(dotB*inv_rms)*beta_scale)
//          + x[t,:]        * (SA + E*sum_{i=1..E} tanh(dotA_i*inv_rms)*alpha_scale)
// dotA_i = sum_d x[d]*w[d]*fnA[d][i] (i=1..4; column 0 unused by the algebra),
// dotB   = sum_d x[d]*w[d]*fnB[d],  inv_rms = rsqrt(mean(x^2)+eps),
// SB = sum(static_beta), SA = sum_{i>=1} sum_j static_alpha[j][i].

#define D_MODEL 2048
#define E_RATE 4
#define HC_EPS 1e-5f
#define NT 256
#define GRID 2048

__device__ __forceinline__ float tanh_fast(float v) {
    // 1 - 2/(e^{2v}+1); exact limits at +-inf, ~1e-6 rel err via v_exp_f32
    float e = __expf(2.0f * v);
    return 1.0f - 2.0f / (e + 1.0f);
}

__device__ __forceinline__ float wave_sum(float v) {
#pragma unroll
    for (int off = 32; off > 0; off >>= 1) v += __shfl_xor(v, off, 64);
    return v;
}

extern "C" __global__ void __launch_bounds__(NT, 3)
hc_kernel(const float* __restrict__ x,
          const float* __restrict__ resid,
          const float* __restrict__ w,
          const float* __restrict__ sA,     // [4][5]
          const float* __restrict__ sB,     // [4]
          const float* __restrict__ fnA,    // [2048][5]
          const float* __restrict__ aScale, // [1]
          const float* __restrict__ fnB,    // [2048]
          const float* __restrict__ bScale, // [1]
          float* __restrict__ out,
          int n_tokens)
{
    __shared__ __align__(16) float P[5][D_MODEL];  // 40 KB: w*fnA[:,1..4], w*fnB

    const int tid  = threadIdx.x;
    const int lane = tid & 63;
    const int wave = tid >> 6;

    // ---- stage fused params into LDS (once per block) ----
    {
        const int d8 = tid * 8;
        float4 w0 = ((const float4*)w)[2 * tid];
        float4 w1 = ((const float4*)w)[2 * tid + 1];
        float4 b0 = ((const float4*)fnB)[2 * tid];
        float4 b1 = ((const float4*)fnB)[2 * tid + 1];
        float w8[8] = {w0.x, w0.y, w0.z, w0.w, w1.x, w1.y, w1.z, w1.w};
        float f8[8] = {b0.x, b0.y, b0.z, b0.w, b1.x, b1.y, b1.z, b1.w};
        float fa[40];
        float4* fap = (float4*)fa;
        const float4* fnA4 = (const float4*)fnA;
#pragma unroll
        for (int j = 0; j < 10; j++) fap[j] = fnA4[tid * 10 + j];
#pragma unroll
        for (int k = 0; k < 8; k++) {
#pragma unroll
            for (int i = 0; i < 4; i++) P[i][d8 + k] = w8[k] * fa[k * 5 + (i + 1)];
            P[4][d8 + k] = w8[k] * f8[k];
        }
    }

    // ---- static scalars (uniform, constant-cached) ----
    const float SB = sB[0] + sB[1] + sB[2] + sB[3];
    float SA = 0.0f;
#pragma unroll
    for (int j = 0; j < 4; j++)
#pragma unroll
        for (int i = 1; i <= 4; i++) SA += sA[j * 5 + i];
    const float asc = aScale[0];
    const float bsc = bScale[0];

    __syncthreads();  // the ONLY barrier — params staged

    // ---- wave-per-token grid-stride loop with x-prefetch ----
    const int gw0 = blockIdx.x * (NT / 64) + wave;
    const int nGW = GRID * (NT / 64);

    float4 xc[8];
    int tk = gw0;
    if (tk < n_tokens) {
        const float4* xr = (const float4*)(x + (size_t)tk * D_MODEL);
#pragma unroll
        for (int c = 0; c < 8; c++) xc[c] = xr[c * 64 + lane];
    }

    for (; tk < n_tokens; tk += nGW) {
        const int nxt = tk + nGW;

        // issue residual loads for this token (needed only at epilogue)
        float4 rc[8];
        const float4* rr = (const float4*)(resid + (size_t)tk * D_MODEL);
#pragma unroll
        for (int c = 0; c < 8; c++) rc[c] = rr[c * 64 + lane];

        // issue x loads for next token (stay in flight across the butterfly)
        float4 xn[8];
        if (nxt < n_tokens) {
            const float4* xr = (const float4*)(x + (size_t)nxt * D_MODEL);
#pragma unroll
            for (int c = 0; c < 8; c++) xn[c] = xr[c * 64 + lane];
        }

        // ---- 6 dot-partials over this lane's 32 elements ----
        float a0 = 0, a1 = 0, a2 = 0, a3 = 0, ab = 0, ssq = 0;
#pragma unroll
        for (int c = 0; c < 8; c++) {
            const float4 xv = xc[c];
            const int off = c * 256 + lane * 4;
            const float4 p0 = *(const float4*)&P[0][off];
            const float4 p1 = *(const float4*)&P[1][off];
            const float4 p2 = *(const float4*)&P[2][off];
            const float4 p3 = *(const float4*)&P[3][off];
            const float4 pb = *(const float4*)&P[4][off];
            ssq += xv.x * xv.x + xv.y * xv.y + xv.z * xv.z + xv.w * xv.w;
            a0  += xv.x * p0.x + xv.y * p0.y + xv.z * p0.z + xv.w * p0.w;
            a1  += xv.x * p1.x + xv.y * p1.y + xv.z * p1.z + xv.w * p1.w;
            a2  += xv.x * p2.x + xv.y * p2.y + xv.z * p2.z + xv.w * p2.w;
            a3  += xv.x * p3.x + xv.y * p3.y + xv.z * p3.z + xv.w * p3.w;
            ab  += xv.x * pb.x + xv.y * pb.y + xv.z * pb.z + xv.w * pb.w;
        }

        // ---- wave-internal reduction (no barriers) ----
        a0 = wave_sum(a0); a1 = wave_sum(a1); a2 = wave_sum(a2);
        a3 = wave_sum(a3); ab = wave_sum(ab); ssq = wave_sum(ssq);

        // ---- coefficients, computed redundantly by all lanes ----
        const float inv = rsqrtf(ssq * (1.0f / D_MODEL) + HC_EPS);
        const float dynA = tanh_fast(a0 * inv) + tanh_fast(a1 * inv) +
                           tanh_fast(a2 * inv) + tanh_fast(a3 * inv);
        const float cX = SA + (float)E_RATE * asc * dynA;
        const float cR = SB + (float)E_RATE * bsc * tanh_fast(ab * inv);

        // ---- epilogue ----
        float4* orow = (float4*)(out + (size_t)tk * D_MODEL);
#pragma unroll
        for (int c = 0; c < 8; c++) {
            float4 o;
            o.x = rc[c].x * cR + xc[c].x * cX;
            o.y = rc[c].y * cR + xc[c].y * cX;
            o.z = rc[c].z * cR + xc[c].z * cX;
            o.w = rc[c].w * cR + xc[c].w * cX;
            orow[c * 64 + lane] = o;
        }

#pragma unroll
        for (int c = 0; c < 8; c++) xc[c] = xn[c];
    }
}

extern "C" void kernel_launch(void* const* d_in, const int* in_sizes, int n_in,
                              void* d_out, int out_size, void* d_ws, size_t ws_size,
                              hipStream_t stream) {
    const float* x      = (const float*)d_in[0];
    const float* resid  = (const float*)d_in[1];
    const float* w      = (const float*)d_in[2];
    const float* sA     = (const float*)d_in[3];
    const float* sB     = (const float*)d_in[4];
    const float* fnA    = (const float*)d_in[5];
    const float* aScale = (const float*)d_in[6];
    const float* fnB    = (const float*)d_in[7];
    const float* bScale = (const float*)d_in[8];
    float* out          = (float*)d_out;

    const int n_tokens = in_sizes[0] / D_MODEL;  // 16384

    hc_kernel<<<GRID, NT, 0, stream>>>(x, resid, w, sA, sB, fnA, aScale,
                                       fnB, bScale, out, n_tokens);
}